// Round 9
// baseline (303.211 us; speedup 1.0000x reference)
//
#include <hip/hip_runtime.h>
#include <hip/hip_bf16.h>

#define H 128
#define NT 4
#define CAP4 40
#define BK 64

typedef __attribute__((ext_vector_type(8))) _Float16 half8;
typedef __attribute__((ext_vector_type(4))) float f32x4;

#if defined(__has_builtin)
#if __has_builtin(__builtin_amdgcn_global_load_lds)
#define HAS_GLL 1
#endif
#endif
#ifndef HAS_GLL
#define HAS_GLL 0
#endif

__device__ __forceinline__ float bf2f(unsigned short u) {
    union { unsigned int i; float f; } v;
    v.i = ((unsigned int)u) << 16;
    return v.f;
}

__device__ __forceinline__ unsigned short f2bf(float f) {
    union { float f; unsigned int i; } v;
    v.f = f;
    unsigned int x = v.i;
    unsigned int r = (x + 0x7fffu + ((x >> 16) & 1u)) >> 16;  // RNE
    return (unsigned short)r;
}

__device__ __forceinline__ float fsigmoid(float x) {
    return 1.0f / (1.0f + __expf(-x));
}
__device__ __forceinline__ float ftanh(float x) {
    return 1.0f - 2.0f / (__expf(2.0f * x) + 1.0f);  // inf-safe both tails
}

// flag-adaptive fp32 read from raw input buffer (1 = bf16-packed, 0 = fp32)
__device__ __forceinline__ float readf(const void* p, long i, int isbf) {
    return isbf ? bf2f(((const unsigned short*)p)[i]) : ((const float*)p)[i];
}

// ---------------------------------------------------------------------------
// async global->LDS 16B
// ---------------------------------------------------------------------------
__device__ __forceinline__ void gll16(const _Float16* g, _Float16* l) {
#if HAS_GLL
    __builtin_amdgcn_global_load_lds(
        (const __attribute__((address_space(1))) unsigned int*)g,
        (__attribute__((address_space(3))) unsigned int*)l, 16, 0, 0);
#endif
}

// ---------------------------------------------------------------------------
// Stage a 128row x 64k fp16 tile into LDS, unpadded (row stride 64 halfs),
// XOR-swizzled: LDS[r][chunk p] holds global chunk (p ^ (r&7)).
// ---------------------------------------------------------------------------
__device__ __forceinline__ void stage_tile(
    const _Float16* __restrict__ gbase, int rstride, int row0, int kof,
    int maxrow, _Float16* lds) {
    const int wave = threadIdx.x >> 6, lane = threadIdx.x & 63;
#pragma unroll
    for (int s = 0; s < 4; s++) {
        int R = wave * 32 + s * 8;               // 8-row group (8-aligned)
        int rl = R + (lane >> 3);
        int rg = row0 + rl;
        if (rg >= maxrow) rg = maxrow - 1;
        int chunk = (lane & 7) ^ (rl & 7);
        const _Float16* gp = gbase + (size_t)rg * rstride + kof + chunk * 8;
#if HAS_GLL
        gll16(gp, lds + R * 64);
#else
        *(half8*)&lds[rl * 64 + (lane & 7) * 8] = *(const half8*)gp;
#endif
    }
}

// fragment read honoring the swizzle: global chunk g (=ks*4+quad) of row r
__device__ __forceinline__ half8 frag(const _Float16* lds, int r, int g) {
    return *(const half8*)&lds[r * 64 + ((g ^ (r & 7)) * 8)];
}

// ---------------------------------------------------------------------------
// dtype detector: low u16 of each dword as bf16 exponent sanity test.
// ---------------------------------------------------------------------------
__global__ void detect_dtype(const unsigned short* __restrict__ states_u16,
                             int* __restrict__ flag) {
    __shared__ int cnt;
    if (threadIdx.x == 0) cnt = 0;
    __syncthreads();
    int local = 0;
    for (int i = threadIdx.x; i < 1024; i += 256) {
        unsigned short u = states_u16[2 * i];
        int e = (u >> 7) & 0xFF;
        if (e >= 96 && e <= 158) local++;
    }
    atomicAdd(&cnt, local);
    __syncthreads();
    if (threadIdx.x == 0) *flag = (cnt >= 512) ? 1 : 0;
}

__global__ void cast_h16(const void* __restrict__ in, _Float16* __restrict__ out,
                         const int* __restrict__ flag, int n) {
    int i = blockIdx.x * blockDim.x + threadIdx.x;
    if (i < n) out[i] = (_Float16)readf(in, i, *flag);
}

// type_W [L][t][k][c] -> BTw [L][c:128][t*128+k : 512]
__global__ void prep_BTw(const void* __restrict__ W, _Float16* __restrict__ BTw,
                         const int* __restrict__ flag, int total) {
    int i = blockIdx.x * 256 + threadIdx.x;
    if (i >= total) return;
    int l = i >> 16;            // 128*512 per layer
    int rem = i & 65535;
    int c = rem >> 9, kk = rem & 511;
    int t = kk >> 7, k = kk & 127;
    BTw[i] = (_Float16)readf(W, (((long)(l * NT + t) * H) + k) * H + c, *flag);
}

// gru kernels -> BTg2 [L][nc:512][k:256], gate-interleaved columns:
//   nc = g*64 + gate*16 + m, actual h-col c = g*16 + m, gate in {z,r,x,h}
__global__ void prep_BTg2(const void* __restrict__ gk, const void* __restrict__ gr,
                          _Float16* __restrict__ BTg, const int* __restrict__ flag,
                          int total) {
    int i = blockIdx.x * 256 + threadIdx.x;
    if (i >= total) return;
    int l = i >> 17;            // 512*256 per layer
    int rem = i & 131071;
    int nc = rem >> 8, k = rem & 255;
    int g = nc >> 6, gate = (nc >> 4) & 3, m = nc & 15;
    int c = g * 16 + m;
    int fl = *flag;
    float v = 0.0f;
    if (gate == 0) {
        v = (k < 128) ? readf(gk, ((long)l * H + k) * 384 + c, fl)
                      : readf(gr, ((long)l * H + (k - 128)) * 384 + c, fl);
    } else if (gate == 1) {
        v = (k < 128) ? readf(gk, ((long)l * H + k) * 384 + 128 + c, fl)
                      : readf(gr, ((long)l * H + (k - 128)) * 384 + 128 + c, fl);
    } else if (gate == 2) {
        if (k < 128) v = readf(gk, ((long)l * H + k) * 384 + 256 + c, fl);
    } else {
        if (k >= 128) v = readf(gr, ((long)l * H + (k - 128)) * 384 + 256 + c, fl);
    }
    BTg[i] = (_Float16)v;
}

// btab[L][t][128]=type_b; gbsum[L][256]=gb0+gb1 (z,r); gb0c/gb1c[L][128] (c-gate)
__global__ void prep_bias2(const void* __restrict__ type_b, const void* __restrict__ grub,
                           float* __restrict__ btab, float* __restrict__ gbsum,
                           float* __restrict__ gb0c, float* __restrict__ gb1c,
                           const int* __restrict__ flag, int LAYERS) {
    int i = blockIdx.x * 256 + threadIdx.x;
    int fl = *flag;
    if (i < LAYERS * NT * H) btab[i] = readf(type_b, i, fl);
    if (i < LAYERS * 256) {
        int l = i >> 8, c = i & 255;
        gbsum[i] = readf(grub, (long)l * 768 + c, fl) +
                   readf(grub, (long)l * 768 + 384 + c, fl);
    }
    if (i < LAYERS * H) {
        int l = i >> 7, c = i & 127;
        gb0c[i] = readf(grub, (long)l * 768 + 256 + c, fl);
        gb1c[i] = readf(grub, (long)l * 768 + 384 + 256 + c, fl);
    }
}

// ---------------------------------------------------------------------------
// bucket edges by (dst, type); counts4 pre-zeroed. counts4[NN][4] doubles as
// the int4 per-row count table for the agg bias epilogue (true counts).
// ---------------------------------------------------------------------------
__global__ void place_edges4(const int* __restrict__ edges, int* __restrict__ counts4,
                             int* __restrict__ buckets4, int NE) {
    int e = blockIdx.x * 256 + threadIdx.x;
    if (e >= NE) return;
    int t = edges[3 * e], src = edges[3 * e + 1], dst = edges[3 * e + 2];
    int slot = atomicAdd(&counts4[dst * 4 + t], 1);
    if (slot < CAP4) buckets4[((size_t)dst * 4 + t) * CAP4 + slot] = src;
}

// ---------------------------------------------------------------------------
// Fused gather + agg GEMM. BM=64 rows/block, N=128, K=512 (chunk kc ->
// type t=kc>>1, col-half hf=kc&1). The A tile is not loaded from memory:
// it is GATHERED per chunk (sum of h16[src] slices over the (row,t) bucket,
// fp32 accumulate, one fp16 round) straight into the swizzled As LDS tile.
// Epilogue adds cnt-weighted type biases. 24 KB LDS -> high occupancy.
// ---------------------------------------------------------------------------
__global__ __launch_bounds__(256) void gather_gemm_agg(
    const _Float16* __restrict__ h16,      // [NN][128]
    const int* __restrict__ counts4,       // [NN][4]
    const int* __restrict__ buckets4,      // [NN][4][CAP4]
    const _Float16* __restrict__ BT,       // [128c][512k] this layer
    const float* __restrict__ btab,        // [4][128]
    _Float16* __restrict__ agg,            // [NN][128]
    int Mrows) {
    __shared__ _Float16 As[64 * 64];
    __shared__ _Float16 Bs[128 * 64];

    const int row0 = blockIdx.x * 64;
    const int tid = threadIdx.x;
    const int wave = tid >> 6, lane = tid & 63;
    const int m = lane & 15, quad = lane >> 4;
    const int wc = wave * 32;            // this wave's 32 output cols

    // gather mapping: thread = (row gr, 16-col slice part)
    const int gr = tid >> 2, part = tid & 3;
    int grow = row0 + gr;
    if (grow >= Mrows) grow = Mrows - 1;

    f32x4 acc[4][2] = {};

    for (int kc = 0; kc < 8; kc++) {
        const int t = kc >> 1, hf = kc & 1;
        __syncthreads();
        stage_tile(BT, 512, 0, kc * BK, 128, Bs);

        // gather this chunk of A: row grow, h-cols [hf*64+part*16, +16)
        {
            int cnt = counts4[grow * 4 + t];
            if (cnt > CAP4) cnt = CAP4;
            const int* bkt = buckets4 + ((size_t)grow * 4 + t) * CAP4;
            float a[16] = {};
            for (int e = 0; e < cnt; e++) {
                const _Float16* hp =
                    &h16[(size_t)bkt[e] * H + hf * 64 + part * 16];
                half8 v0 = *(const half8*)hp;
                half8 v1 = *(const half8*)(hp + 8);
#pragma unroll
                for (int j = 0; j < 8; j++) {
                    a[j] += (float)v0[j];
                    a[8 + j] += (float)v1[j];
                }
            }
            half8 o0, o1;
#pragma unroll
            for (int j = 0; j < 8; j++) {
                o0[j] = (_Float16)a[j];
                o1[j] = (_Float16)a[8 + j];
            }
            const int p0 = part * 2;
            *(half8*)&As[gr * 64 + ((p0 ^ (gr & 7)) * 8)] = o0;
            *(half8*)&As[gr * 64 + (((p0 + 1) ^ (gr & 7)) * 8)] = o1;
        }
        __syncthreads();

#pragma unroll
        for (int ks = 0; ks < 2; ks++) {
            half8 a[4], b[2];
#pragma unroll
            for (int mt = 0; mt < 4; mt++)
                a[mt] = frag(As, mt * 16 + m, ks * 4 + quad);
#pragma unroll
            for (int nt = 0; nt < 2; nt++)
                b[nt] = frag(Bs, wc + nt * 16 + m, ks * 4 + quad);
#pragma unroll
            for (int mt = 0; mt < 4; mt++)
#pragma unroll
                for (int nt = 0; nt < 2; nt++)
                    acc[mt][nt] = __builtin_amdgcn_mfma_f32_16x16x32_f16(
                        a[mt], b[nt], acc[mt][nt], 0, 0, 0);
        }
    }

    const int4* cnt4 = (const int4*)counts4;
#pragma unroll
    for (int mt = 0; mt < 4; mt++) {
#pragma unroll
        for (int i = 0; i < 4; i++) {
            int row = row0 + mt * 16 + quad * 4 + i;
            if (row >= Mrows) continue;
            int4 c4 = cnt4[row];
#pragma unroll
            for (int nt = 0; nt < 2; nt++) {
                int cl = wc + nt * 16 + m;
                float bias = c4.x * btab[cl] + c4.y * btab[128 + cl] +
                             c4.z * btab[256 + cl] + c4.w * btab[384 + cl];
                agg[(size_t)row * H + cl] = (_Float16)(acc[mt][nt][i] + bias);
            }
        }
    }
}

// ---------------------------------------------------------------------------
// GRU GEMM with fused gate epilogue. 1-D grid with XCD-aware swizzle.
// Zero-K skip: x-gate (nt=2) has support only on K<128, h-gate (nt=3) only
// on K>=128 -> per kc iterate nt in {0,1,2} or {0,1,3} (25% MFMA saved).
// ---------------------------------------------------------------------------
__global__ __launch_bounds__(256) void gru_gemm_gate(
    const _Float16* __restrict__ agg16,  // [NN][128]
    const _Float16* __restrict__ h16,    // [NN][128]
    const _Float16* __restrict__ BT,     // [512nc][256k]
    const float* __restrict__ gbsum,     // [256]
    const float* __restrict__ gb0c,      // [128]
    const float* __restrict__ gb1c,      // [128]
    _Float16* __restrict__ hnext,        // [NN][128]
    void* __restrict__ outbuf,           // final output or nullptr
    const int* __restrict__ flag, int rtiles, int NN) {
    __shared__ _Float16 As[128 * 64];
    __shared__ _Float16 Bs[128 * 64];
    __shared__ _Float16 hg[128 * 32];    // h cols [32y, 32y+32) for gate blend

    // swizzle decode: b = macro*32 + y*8 + r_lo ; r = macro*8 + r_lo
    const int b = blockIdx.x;
    const int r_lo = b & 7, y = (b >> 3) & 3, macro = b >> 5;
    const int rt = macro * 8 + r_lo;
    if (rt >= rtiles) return;
    const int row0 = rt * 128;
    const int col0 = y * 128;
    const int tid = threadIdx.x;
    const int wave = tid >> 6, lane = tid & 63;
    const int m = lane & 15, quad = lane >> 4;
    const int wr = (wave & 1) * 64, wc = (wave >> 1) * 64;

    f32x4 acc[4][4] = {};

    for (int kc = 0; kc < 4; kc++) {
        const int k0 = kc * BK;
        const int ntA = (kc < 2) ? 2 : 3;   // zero-K skip: 3rd active gate
        __syncthreads();
        if (kc < 2) stage_tile(agg16, H, row0, k0, NN, As);
        else        stage_tile(h16, H, row0, k0 - 128, NN, As);
        stage_tile(BT, 256, col0, k0, 512, Bs);
        if (kc == 0) {
#pragma unroll
            for (int s = 0; s < 2; s++) {       // hg: 128 rows x 32 cols
                int idx = s * 256 + tid;
                int r = idx >> 2, cseg = (idx & 3) * 8;
                int rg = row0 + r;
                if (rg >= NN) rg = NN - 1;
                *(half8*)&hg[r * 32 + cseg] =
                    *(const half8*)&h16[(size_t)rg * H + y * 32 + cseg];
            }
        }
        __syncthreads();

#pragma unroll
        for (int ks = 0; ks < 2; ks++) {
            half8 a[4], b8[3];
#pragma unroll
            for (int mt = 0; mt < 4; mt++)
                a[mt] = frag(As, wr + mt * 16 + m, ks * 4 + quad);
            b8[0] = frag(Bs, wc + 0 * 16 + m, ks * 4 + quad);
            b8[1] = frag(Bs, wc + 1 * 16 + m, ks * 4 + quad);
            b8[2] = frag(Bs, wc + ntA * 16 + m, ks * 4 + quad);
#pragma unroll
            for (int mt = 0; mt < 4; mt++) {
                acc[mt][0] = __builtin_amdgcn_mfma_f32_16x16x32_f16(
                    a[mt], b8[0], acc[mt][0], 0, 0, 0);
                acc[mt][1] = __builtin_amdgcn_mfma_f32_16x16x32_f16(
                    a[mt], b8[1], acc[mt][1], 0, 0, 0);
                acc[mt][ntA] = __builtin_amdgcn_mfma_f32_16x16x32_f16(
                    a[mt], b8[2], acc[mt][ntA], 0, 0, 0);
            }
        }
    }

    // gate epilogue: this wave's col-group
    const int g = (col0 + wc) >> 6;      // 0..7
    const int c = g * 16 + m;            // h-column
    const int chg = (wc >> 2) + m;       // c - 32y
    const float bz = gbsum[c];
    const float br = gbsum[128 + c];
    const float bx = gb0c[c];
    const float bh = gb1c[c];
    const int fl = outbuf ? *flag : 0;

#pragma unroll
    for (int mt = 0; mt < 4; mt++) {
#pragma unroll
        for (int i = 0; i < 4; i++) {
            int rl = wr + mt * 16 + quad * 4 + i;
            int row = row0 + rl;
            if (row >= NN) continue;
            float z = fsigmoid(acc[mt][0][i] + bz);
            float r = fsigmoid(acc[mt][1][i] + br);
            float cc = ftanh((acc[mt][2][i] + bx) + r * (acc[mt][3][i] + bh));
            float hv = (float)hg[rl * 32 + chg];
            float hn = z * hv + (1.0f - z) * cc;
            size_t oi = (size_t)row * H + c;
            hnext[oi] = (_Float16)hn;
            if (outbuf) {
                if (fl) ((unsigned short*)outbuf)[oi] = f2bf(hn);
                else    ((float*)outbuf)[oi] = hn;
            }
        }
    }
}

// ---------------------------------------------------------------------------
extern "C" void kernel_launch(void* const* d_in, const int* in_sizes, int n_in,
                              void* d_out, int out_size, void* d_ws, size_t ws_size,
                              hipStream_t stream) {
    const void* states = d_in[0];
    const int*  edges  = (const int*)d_in[1];
    const void* type_W = d_in[2];
    const void* type_b = d_in[3];
    const void* gruk   = d_in[4];
    const void* grur   = d_in[5];
    const void* grub   = d_in[6];

    const int NN = in_sizes[0] / H;    // 50000
    const int NE = in_sizes[1] / 3;    // 400000
    const int nW = in_sizes[2];        // L*NT*128*128
    const int LAYERS = nW / (NT * H * H);

    // --- workspace layout ---
    char* w = (char*)d_ws;
    int* flag = (int*)w;                               w += 64;
    _Float16* h16A  = (_Float16*)w;                    w += (size_t)NN * H * 2;
    _Float16* h16B  = (_Float16*)w;                    w += (size_t)NN * H * 2;
    _Float16* agg16 = (_Float16*)w;                    w += (size_t)NN * H * 2;
    _Float16* BTw = (_Float16*)w;                      w += (size_t)LAYERS * H * 512 * 2;
    _Float16* BTg = (_Float16*)w;                      w += (size_t)LAYERS * 512 * 256 * 2;
    float* btab  = (float*)w;                          w += (size_t)LAYERS * NT * H * 4;
    float* gbsum = (float*)w;                          w += (size_t)LAYERS * 256 * 4;
    float* gb0c  = (float*)w;                          w += (size_t)LAYERS * H * 4;
    float* gb1c  = (float*)w;                          w += (size_t)LAYERS * H * 4;
    int* counts4 = (int*)w;                            w += (size_t)NN * 4 * 4;
    int* buckets4 = (int*)w;                           // [NN][4][CAP4]

    detect_dtype<<<1, 256, 0, stream>>>((const unsigned short*)states, flag);

    cast_h16<<<(NN * H + 255) / 256, 256, 0, stream>>>(states, h16A, flag, NN * H);
    prep_BTw<<<(LAYERS * 65536 + 255) / 256, 256, 0, stream>>>(type_W, BTw, flag,
                                                               LAYERS * 65536);
    prep_BTg2<<<(LAYERS * 131072 + 255) / 256, 256, 0, stream>>>(gruk, grur, BTg, flag,
                                                                 LAYERS * 131072);
    prep_bias2<<<4, 256, 0, stream>>>(type_b, grub, btab, gbsum, gb0c, gb1c, flag, LAYERS);

    hipMemsetAsync(counts4, 0, (size_t)NN * 4 * 4, stream);
    place_edges4<<<(NE + 255) / 256, 256, 0, stream>>>(edges, counts4, buckets4, NE);

    const int rtiles = (NN + 127) / 128;
    const int atiles = (NN + 63) / 64;
    const int nb_gru = ((rtiles + 7) / 8) * 32;
    for (int L = 0; L < LAYERS; L++) {
        const _Float16* hcur = (L & 1) ? h16B : h16A;
        _Float16* hnext      = (L & 1) ? h16A : h16B;

        gather_gemm_agg<<<atiles, 256, 0, stream>>>(
            hcur, counts4, buckets4,
            BTw + (size_t)L * H * 512, btab + (size_t)L * NT * H,
            agg16, NN);

        gru_gemm_gate<<<nb_gru, 256, 0, stream>>>(
            agg16, hcur,
            BTg + (size_t)L * 512 * 256,
            gbsum + (size_t)L * 256, gb0c + (size_t)L * H, gb1c + (size_t)L * H,
            hnext, (L == LAYERS - 1) ? d_out : nullptr, flag, rtiles, NN);
    }
}

// Round 10
// 290.193 us; speedup vs baseline: 1.0449x; 1.0449x over previous
//
#include <hip/hip_runtime.h>
#include <hip/hip_bf16.h>

#define H 128
#define NT 4
#define CAP4 40
#define BK 64

typedef __attribute__((ext_vector_type(8))) _Float16 half8;
typedef __attribute__((ext_vector_type(4))) float f32x4;

#if defined(__has_builtin)
#if __has_builtin(__builtin_amdgcn_global_load_lds)
#define HAS_GLL 1
#endif
#endif
#ifndef HAS_GLL
#define HAS_GLL 0
#endif

__device__ __forceinline__ float bf2f(unsigned short u) {
    union { unsigned int i; float f; } v;
    v.i = ((unsigned int)u) << 16;
    return v.f;
}

__device__ __forceinline__ unsigned short f2bf(float f) {
    union { float f; unsigned int i; } v;
    v.f = f;
    unsigned int x = v.i;
    unsigned int r = (x + 0x7fffu + ((x >> 16) & 1u)) >> 16;  // RNE
    return (unsigned short)r;
}

__device__ __forceinline__ float fsigmoid(float x) {
    return 1.0f / (1.0f + __expf(-x));
}
__device__ __forceinline__ float ftanh(float x) {
    return 1.0f - 2.0f / (__expf(2.0f * x) + 1.0f);  // inf-safe both tails
}

// flag-adaptive fp32 read from raw input buffer (1 = bf16-packed, 0 = fp32)
__device__ __forceinline__ float readf(const void* p, long i, int isbf) {
    return isbf ? bf2f(((const unsigned short*)p)[i]) : ((const float*)p)[i];
}

// ---------------------------------------------------------------------------
// async global->LDS 16B
// ---------------------------------------------------------------------------
__device__ __forceinline__ void gll16(const _Float16* g, _Float16* l) {
#if HAS_GLL
    __builtin_amdgcn_global_load_lds(
        (const __attribute__((address_space(1))) unsigned int*)g,
        (__attribute__((address_space(3))) unsigned int*)l, 16, 0, 0);
#endif
}

// ---------------------------------------------------------------------------
// Stage a 128row x 64k fp16 tile into LDS, unpadded (row stride 64 halfs),
// XOR-swizzled: LDS[r][chunk p] holds global chunk (p ^ (r&7)).
// ---------------------------------------------------------------------------
__device__ __forceinline__ void stage_tile(
    const _Float16* __restrict__ gbase, int rstride, int row0, int kof,
    int maxrow, _Float16* lds) {
    const int wave = threadIdx.x >> 6, lane = threadIdx.x & 63;
#pragma unroll
    for (int s = 0; s < 4; s++) {
        int R = wave * 32 + s * 8;               // 8-row group (8-aligned)
        int rl = R + (lane >> 3);
        int rg = row0 + rl;
        if (rg >= maxrow) rg = maxrow - 1;
        int chunk = (lane & 7) ^ (rl & 7);
        const _Float16* gp = gbase + (size_t)rg * rstride + kof + chunk * 8;
#if HAS_GLL
        gll16(gp, lds + R * 64);
#else
        *(half8*)&lds[rl * 64 + (lane & 7) * 8] = *(const half8*)gp;
#endif
    }
}

// fragment read honoring the swizzle: global chunk g (=ks*4+quad) of row r
__device__ __forceinline__ half8 frag(const _Float16* lds, int r, int g) {
    return *(const half8*)&lds[r * 64 + ((g ^ (r & 7)) * 8)];
}

// ---------------------------------------------------------------------------
// dtype detector: low u16 of each dword as bf16 exponent sanity test.
// ---------------------------------------------------------------------------
__global__ void detect_dtype(const unsigned short* __restrict__ states_u16,
                             int* __restrict__ flag) {
    __shared__ int cnt;
    if (threadIdx.x == 0) cnt = 0;
    __syncthreads();
    int local = 0;
    for (int i = threadIdx.x; i < 1024; i += 256) {
        unsigned short u = states_u16[2 * i];
        int e = (u >> 7) & 0xFF;
        if (e >= 96 && e <= 158) local++;
    }
    atomicAdd(&cnt, local);
    __syncthreads();
    if (threadIdx.x == 0) *flag = (cnt >= 512) ? 1 : 0;
}

// ---------------------------------------------------------------------------
// prep_all: single consolidated prep kernel (one launch replaces 5):
//   seg 0: states -> h16 (fp16)
//   seg 1: type_W [L][t][k][c] -> BTw [L][c:128][t*128+k:512]
//   seg 2: gru kernels -> BTg2 [L][nc:512][k:256] gate-interleaved
//   seg 3: zero counts4
//   seg 4: biases -> btab/gbsum/gb0c/gb1c
// ---------------------------------------------------------------------------
__global__ void prep_all(
    const void* __restrict__ states, const void* __restrict__ type_W,
    const void* __restrict__ type_b, const void* __restrict__ gk,
    const void* __restrict__ gr, const void* __restrict__ grub,
    _Float16* __restrict__ h16, _Float16* __restrict__ BTw,
    _Float16* __restrict__ BTg, float* __restrict__ btab,
    float* __restrict__ gbsum, float* __restrict__ gb0c,
    float* __restrict__ gb1c, int* __restrict__ counts4,
    const int* __restrict__ flag,
    long NNH, int nBTw, int nBTg, int NC4, int LAYERS) {
    long i = (long)blockIdx.x * 256 + threadIdx.x;
    const int fl = *flag;
    if (i < NNH) {                                  // seg 0
        h16[i] = (_Float16)readf(states, i, fl);
        return;
    }
    i -= NNH;
    if (i < nBTw) {                                 // seg 1
        int l = (int)(i >> 16);
        int rem = (int)(i & 65535);
        int c = rem >> 9, kk = rem & 511;
        int t = kk >> 7, k = kk & 127;
        BTw[i] = (_Float16)readf(type_W, (((long)(l * NT + t) * H) + k) * H + c, fl);
        return;
    }
    i -= nBTw;
    if (i < nBTg) {                                 // seg 2
        int l = (int)(i >> 17);
        int rem = (int)(i & 131071);
        int nc = rem >> 8, k = rem & 255;
        int g = nc >> 6, gate = (nc >> 4) & 3, m = nc & 15;
        int c = g * 16 + m;
        float v = 0.0f;
        if (gate == 0) {
            v = (k < 128) ? readf(gk, ((long)l * H + k) * 384 + c, fl)
                          : readf(gr, ((long)l * H + (k - 128)) * 384 + c, fl);
        } else if (gate == 1) {
            v = (k < 128) ? readf(gk, ((long)l * H + k) * 384 + 128 + c, fl)
                          : readf(gr, ((long)l * H + (k - 128)) * 384 + 128 + c, fl);
        } else if (gate == 2) {
            if (k < 128) v = readf(gk, ((long)l * H + k) * 384 + 256 + c, fl);
        } else {
            if (k >= 128) v = readf(gr, ((long)l * H + (k - 128)) * 384 + 256 + c, fl);
        }
        BTg[i] = (_Float16)v;
        return;
    }
    i -= nBTg;
    if (i < NC4) {                                  // seg 3
        counts4[i] = 0;
        return;
    }
    i -= NC4;
    {                                               // seg 4 (i < LAYERS*NT*H)
        int j = (int)i;
        if (j < LAYERS * NT * H) btab[j] = readf(type_b, j, fl);
        if (j < LAYERS * 256) {
            int l = j >> 8, c = j & 255;
            gbsum[j] = readf(grub, (long)l * 768 + c, fl) +
                       readf(grub, (long)l * 768 + 384 + c, fl);
        }
        if (j < LAYERS * H) {
            int l = j >> 7, c = j & 127;
            gb0c[j] = readf(grub, (long)l * 768 + 256 + c, fl);
            gb1c[j] = readf(grub, (long)l * 768 + 384 + 256 + c, fl);
        }
    }
}

// ---------------------------------------------------------------------------
// bucket edges by (dst, type); counts4 zeroed by prep_all. counts4[NN][4]
// doubles as the int4 per-row count table for gemm_agg's bias epilogue.
// ---------------------------------------------------------------------------
__global__ void place_edges4(const int* __restrict__ edges, int* __restrict__ counts4,
                             int* __restrict__ buckets4, int NE) {
    int e = blockIdx.x * 256 + threadIdx.x;
    if (e >= NE) return;
    int t = edges[3 * e], src = edges[3 * e + 1], dst = edges[3 * e + 2];
    int slot = atomicAdd(&counts4[dst * 4 + t], 1);
    if (slot < CAP4) buckets4[((size_t)dst * 4 + t) * CAP4 + slot] = src;
}

// ---------------------------------------------------------------------------
// gather4: one wave per node; quarter-wave q owns type-q's edge list.
// Lane i of group q reads h16[src][i*8 .. i*8+8) (16 lanes x 16B = one row).
// ---------------------------------------------------------------------------
__global__ __launch_bounds__(256) void gather4(
    const _Float16* __restrict__ h16, const int* __restrict__ counts4,
    const int* __restrict__ buckets4, _Float16* __restrict__ A4, int NN) {
    int node = blockIdx.x * 4 + (threadIdx.x >> 6);
    int lane = threadIdx.x & 63;
    int q = lane >> 4, i = lane & 15;
    if (node >= NN) return;
    int cnt = counts4[node * 4 + q];
    if (cnt > CAP4) cnt = CAP4;
    const int* bkt = buckets4 + ((size_t)node * 4 + q) * CAP4;

    float acc[8] = {};
    int e = 0;
    for (; e + 2 <= cnt; e += 2) {
        int s0 = bkt[e], s1 = bkt[e + 1];
        half8 v0 = *(const half8*)&h16[(size_t)s0 * H + i * 8];
        half8 v1 = *(const half8*)&h16[(size_t)s1 * H + i * 8];
#pragma unroll
        for (int j = 0; j < 8; j++) acc[j] += (float)v0[j] + (float)v1[j];
    }
    if (e < cnt) {
        int s0 = bkt[e];
        half8 v0 = *(const half8*)&h16[(size_t)s0 * H + i * 8];
#pragma unroll
        for (int j = 0; j < 8; j++) acc[j] += (float)v0[j];
    }

    half8 o;
#pragma unroll
    for (int j = 0; j < 8; j++) o[j] = (_Float16)acc[j];
    *(half8*)&A4[((size_t)node * 4 + q) * H + i * 8] = o;
}

// ---------------------------------------------------------------------------
// agg GEMM: agg[row][c] = sum_k A4[row][k] * BTw[c][k] + cnt-weighted bias
// Block 128x128, K=512 (8 chunks of 64), 4 waves each 64x64.
// ---------------------------------------------------------------------------
__global__ __launch_bounds__(256) void gemm_agg(
    const _Float16* __restrict__ A4,    // [NN][512]
    const _Float16* __restrict__ BT,    // [128c][512k]
    _Float16* __restrict__ agg,         // [NN][128]
    const int4* __restrict__ cnt4, const float* __restrict__ btab,
    int Mrows) {
    __shared__ _Float16 As[128 * 64];
    __shared__ _Float16 Bs[128 * 64];

    const int row0 = blockIdx.x * 128;
    const int tid = threadIdx.x;
    const int wave = tid >> 6, lane = tid & 63;
    const int m = lane & 15, quad = lane >> 4;
    const int wr = (wave & 1) * 64, wc = (wave >> 1) * 64;

    f32x4 acc[4][4] = {};

    for (int kc = 0; kc < 8; kc++) {
        const int k0 = kc * BK;
        __syncthreads();
        stage_tile(A4, 512, row0, k0, Mrows, As);
        stage_tile(BT, 512, 0, k0, 128, Bs);
        __syncthreads();

#pragma unroll
        for (int ks = 0; ks < 2; ks++) {
            half8 a[4], b[4];
#pragma unroll
            for (int mt = 0; mt < 4; mt++)
                a[mt] = frag(As, wr + mt * 16 + m, ks * 4 + quad);
#pragma unroll
            for (int nt = 0; nt < 4; nt++)
                b[nt] = frag(Bs, wc + nt * 16 + m, ks * 4 + quad);
#pragma unroll
            for (int mt = 0; mt < 4; mt++)
#pragma unroll
                for (int nt = 0; nt < 4; nt++)
                    acc[mt][nt] = __builtin_amdgcn_mfma_f32_16x16x32_f16(
                        a[mt], b[nt], acc[mt][nt], 0, 0, 0);
        }
    }

#pragma unroll
    for (int mt = 0; mt < 4; mt++) {
#pragma unroll
        for (int i = 0; i < 4; i++) {
            int row = row0 + wr + mt * 16 + quad * 4 + i;
            if (row >= Mrows) continue;
            int4 c4 = cnt4[row];
#pragma unroll
            for (int nt = 0; nt < 4; nt++) {
                int cl = wc + nt * 16 + m;
                float bias = c4.x * btab[cl] + c4.y * btab[128 + cl] +
                             c4.z * btab[256 + cl] + c4.w * btab[384 + cl];
                agg[(size_t)row * H + cl] = (_Float16)(acc[mt][nt][i] + bias);
            }
        }
    }
}

// ---------------------------------------------------------------------------
// GRU GEMM with fused gate epilogue. 1-D grid with XCD-aware swizzle.
// Zero-K skip: x-gate (nt=2) has support only on K<128, h-gate (nt=3) only
// on K>=128 -> per kc iterate nt in {0,1,2} or {0,1,3} (25% MFMA saved;
// validated round 9: identical absmax).
// ---------------------------------------------------------------------------
__global__ __launch_bounds__(256) void gru_gemm_gate(
    const _Float16* __restrict__ agg16,  // [NN][128]
    const _Float16* __restrict__ h16,    // [NN][128]
    const _Float16* __restrict__ BT,     // [512nc][256k]
    const float* __restrict__ gbsum,     // [256]
    const float* __restrict__ gb0c,      // [128]
    const float* __restrict__ gb1c,      // [128]
    _Float16* __restrict__ hnext,        // [NN][128]
    void* __restrict__ outbuf,           // final output or nullptr
    const int* __restrict__ flag, int rtiles, int NN) {
    __shared__ _Float16 As[128 * 64];
    __shared__ _Float16 Bs[128 * 64];
    __shared__ _Float16 hg[128 * 32];    // h cols [32y, 32y+32) for gate blend

    // swizzle decode: b = macro*32 + y*8 + r_lo ; r = macro*8 + r_lo
    const int b = blockIdx.x;
    const int r_lo = b & 7, y = (b >> 3) & 3, macro = b >> 5;
    const int rt = macro * 8 + r_lo;
    if (rt >= rtiles) return;
    const int row0 = rt * 128;
    const int col0 = y * 128;
    const int tid = threadIdx.x;
    const int wave = tid >> 6, lane = tid & 63;
    const int m = lane & 15, quad = lane >> 4;
    const int wr = (wave & 1) * 64, wc = (wave >> 1) * 64;

    f32x4 acc[4][4] = {};

    for (int kc = 0; kc < 4; kc++) {
        const int k0 = kc * BK;
        const int ntA = (kc < 2) ? 2 : 3;   // zero-K skip: 3rd active gate
        __syncthreads();
        if (kc < 2) stage_tile(agg16, H, row0, k0, NN, As);
        else        stage_tile(h16, H, row0, k0 - 128, NN, As);
        stage_tile(BT, 256, col0, k0, 512, Bs);
        if (kc == 0) {
#pragma unroll
            for (int s = 0; s < 2; s++) {       // hg: 128 rows x 32 cols
                int idx = s * 256 + tid;
                int r = idx >> 2, cseg = (idx & 3) * 8;
                int rg = row0 + r;
                if (rg >= NN) rg = NN - 1;
                *(half8*)&hg[r * 32 + cseg] =
                    *(const half8*)&h16[(size_t)rg * H + y * 32 + cseg];
            }
        }
        __syncthreads();

#pragma unroll
        for (int ks = 0; ks < 2; ks++) {
            half8 a[4], b8[3];
#pragma unroll
            for (int mt = 0; mt < 4; mt++)
                a[mt] = frag(As, wr + mt * 16 + m, ks * 4 + quad);
            b8[0] = frag(Bs, wc + 0 * 16 + m, ks * 4 + quad);
            b8[1] = frag(Bs, wc + 1 * 16 + m, ks * 4 + quad);
            b8[2] = frag(Bs, wc + ntA * 16 + m, ks * 4 + quad);
#pragma unroll
            for (int mt = 0; mt < 4; mt++) {
                acc[mt][0] = __builtin_amdgcn_mfma_f32_16x16x32_f16(
                    a[mt], b8[0], acc[mt][0], 0, 0, 0);
                acc[mt][1] = __builtin_amdgcn_mfma_f32_16x16x32_f16(
                    a[mt], b8[1], acc[mt][1], 0, 0, 0);
                acc[mt][ntA] = __builtin_amdgcn_mfma_f32_16x16x32_f16(
                    a[mt], b8[2], acc[mt][ntA], 0, 0, 0);
            }
        }
    }

    // gate epilogue: this wave's col-group
    const int g = (col0 + wc) >> 6;      // 0..7
    const int c = g * 16 + m;            // h-column
    const int chg = (wc >> 2) + m;       // c - 32y
    const float bz = gbsum[c];
    const float br = gbsum[128 + c];
    const float bx = gb0c[c];
    const float bh = gb1c[c];
    const int fl = outbuf ? *flag : 0;

#pragma unroll
    for (int mt = 0; mt < 4; mt++) {
#pragma unroll
        for (int i = 0; i < 4; i++) {
            int rl = wr + mt * 16 + quad * 4 + i;
            int row = row0 + rl;
            if (row >= NN) continue;
            float z = fsigmoid(acc[mt][0][i] + bz);
            float r = fsigmoid(acc[mt][1][i] + br);
            float cc = ftanh((acc[mt][2][i] + bx) + r * (acc[mt][3][i] + bh));
            float hv = (float)hg[rl * 32 + chg];
            float hn = z * hv + (1.0f - z) * cc;
            size_t oi = (size_t)row * H + c;
            hnext[oi] = (_Float16)hn;
            if (outbuf) {
                if (fl) ((unsigned short*)outbuf)[oi] = f2bf(hn);
                else    ((float*)outbuf)[oi] = hn;
            }
        }
    }
}

// ---------------------------------------------------------------------------
extern "C" void kernel_launch(void* const* d_in, const int* in_sizes, int n_in,
                              void* d_out, int out_size, void* d_ws, size_t ws_size,
                              hipStream_t stream) {
    const void* states = d_in[0];
    const int*  edges  = (const int*)d_in[1];
    const void* type_W = d_in[2];
    const void* type_b = d_in[3];
    const void* gruk   = d_in[4];
    const void* grur   = d_in[5];
    const void* grub   = d_in[6];

    const int NN = in_sizes[0] / H;    // 50000
    const int NE = in_sizes[1] / 3;    // 400000
    const int nW = in_sizes[2];        // L*NT*128*128
    const int LAYERS = nW / (NT * H * H);

    // --- workspace layout ---
    char* w = (char*)d_ws;
    int* flag = (int*)w;                               w += 64;
    _Float16* h16A  = (_Float16*)w;                    w += (size_t)NN * H * 2;
    _Float16* h16B  = (_Float16*)w;                    w += (size_t)NN * H * 2;
    _Float16* agg16 = (_Float16*)w;                    w += (size_t)NN * H * 2;
    _Float16* A4    = (_Float16*)w;                    w += (size_t)NN * 4 * H * 2;
    _Float16* BTw = (_Float16*)w;                      w += (size_t)LAYERS * H * 512 * 2;
    _Float16* BTg = (_Float16*)w;                      w += (size_t)LAYERS * 512 * 256 * 2;
    float* btab  = (float*)w;                          w += (size_t)LAYERS * NT * H * 4;
    float* gbsum = (float*)w;                          w += (size_t)LAYERS * 256 * 4;
    float* gb0c  = (float*)w;                          w += (size_t)LAYERS * H * 4;
    float* gb1c  = (float*)w;                          w += (size_t)LAYERS * H * 4;
    int* counts4 = (int*)w;                            w += (size_t)NN * 4 * 4;
    int* buckets4 = (int*)w;                           // [NN][4][CAP4]

    detect_dtype<<<1, 256, 0, stream>>>((const unsigned short*)states, flag);

    const long NNH = (long)NN * H;
    const int nBTw = LAYERS * 65536;
    const int nBTg = LAYERS * 131072;
    const int NC4 = NN * 4;
    const long ptotal = NNH + nBTw + nBTg + NC4 + LAYERS * NT * H;
    prep_all<<<(int)((ptotal + 255) / 256), 256, 0, stream>>>(
        states, type_W, type_b, gruk, grur, grub,
        h16A, BTw, BTg, btab, gbsum, gb0c, gb1c, counts4, flag,
        NNH, nBTw, nBTg, NC4, LAYERS);

    place_edges4<<<(NE + 255) / 256, 256, 0, stream>>>(edges, counts4, buckets4, NE);

    const int rtiles = (NN + 127) / 128;
    const int nb_gru = ((rtiles + 7) / 8) * 32;
    for (int L = 0; L < LAYERS; L++) {
        const _Float16* hcur = (L & 1) ? h16B : h16A;
        _Float16* hnext      = (L & 1) ? h16A : h16B;

        gather4<<<(NN + 3) / 4, 256, 0, stream>>>(hcur, counts4, buckets4, A4, NN);

        gemm_agg<<<rtiles, 256, 0, stream>>>(
            A4, BTw + (size_t)L * H * 512, agg16,
            (const int4*)counts4, btab + (size_t)L * NT * H, NN);

        gru_gemm_gate<<<nb_gru, 256, 0, stream>>>(
            agg16, hcur,
            BTg + (size_t)L * 512 * 256,
            gbsum + (size_t)L * 256, gb0c + (size_t)L * H, gb1c + (size_t)L * H,
            hnext, (L == LAYERS - 1) ? d_out : nullptr, flag, rtiles, NN);
    }
}